// Round 3
// baseline (3130.752 us; speedup 1.0000x reference)
//
#include <hip/hip_runtime.h>

// Bidirectional LSTM: V=32000, H=1024, S=512. fp32 in/out.
// SINGLE fused persistent kernel, 256 blocks x 256 threads (1 block/CU).
//
// Round-3: exchange made sentinel-based.
//  - flg[2][2][128] u32: one tag per producer block (4 cache lines/dir/par).
//    Consumers poll FLAGS only (16x fewer line-requests than sweeping the
//    8KB h array). Data words keep embedded tags and are verified after
//    load (straggler reload loop) -> correctness never relies on store
//    ordering; flags are a pure accelerator.
//  - Data loads issued right after flag barrier, acc_x runs on top of them
//    (hides ~600cy load latency for the critical block).
//  - Per-wave stage-c: each wave owns 2 units; row sums are wave-resident
//    after the kc-butterfly -> gates + combine via __shfl, no g_red, no
//    third barrier.
//  - Self-zeroing of exchange words at init by their own future publishers
//    (closes t=511 stale-tag spurious match vs previous-dispatch residue).

#define HID 1024
#define SEQ 512

__device__ __forceinline__ unsigned int f2bf(float f) {
  union { float f; unsigned int i; } v; v.f = f;
  unsigned int u = v.i;
  return (u + 0x7fffu + ((u >> 16) & 1u)) >> 16;  // RNE
}
__device__ __forceinline__ unsigned int pk(float lo, float hi) {
  return f2bf(lo) | (f2bf(hi) << 16);
}
__device__ __forceinline__ float bflo(unsigned int u) {
  union { unsigned int i; float f; } v; v.i = u << 16; return v.f;
}
__device__ __forceinline__ float bfhi(unsigned int u) {
  union { unsigned int i; float f; } v; v.i = u & 0xffff0000u; return v.f;
}
__device__ __forceinline__ float sigm(float x) { return 1.f / (1.f + __expf(-x)); }
__device__ __forceinline__ float ftanh(float x) {
  return 1.f - 2.f / (__expf(2.f * x) + 1.f);   // exact at saturation
}

__global__ __launch_bounds__(256, 1)
void bilstm_kernel(const int* __restrict__ tokens,
                   const float* __restrict__ emb,
                   const float* __restrict__ Wxf, const float* __restrict__ Whf,
                   const float* __restrict__ bxf, const float* __restrict__ bhf,
                   const float* __restrict__ Wxb, const float* __restrict__ Whb,
                   const float* __restrict__ bxb, const float* __restrict__ bhb,
                   unsigned long long* h_ex,   // [2][2][1024] u64 {tag|h}
                   unsigned int* flg,          // [2][2][128]  u32 tags
                   float* __restrict__ out)    // [SEQ][2048] fp32
{
  extern __shared__ unsigned char smem[];      // 64KB: wx bf16-packed
  uint4* wx_lds = (uint4*)smem;                // wx_lds[m*256 + tid]
  __shared__ alignas(16) float hs[HID];
  __shared__ alignas(16) float xbuf[2][HID];
  __shared__ int tok_s[SEQ];

  const int b   = blockIdx.x;
  const int d   = (b & 7) >> 2;                // dir by XCD half
  const int db  = (b >> 3) * 4 + (b & 3);      // 0..127 within direction
  const int tid = threadIdx.x;
  const int r   = tid >> 3;                    // 0..31: row = unit_l*4+gate
  const int kc  = tid & 7;                     // 8-way k split
  const int wv  = tid >> 6, lane = tid & 63;
  const int ul  = r >> 2;                      // local unit 0..7
  const int gate = r & 3;
  const int unit = db * 8 + ul;
  const float* Wh  = d ? Whb : Whf;
  const float* Wxp = d ? Wxb : Wxf;

  // --- init: Wh slice -> registers, Wx slice -> LDS (bf16 pairs) ---
  float w[128];
  {
    const float* wrow = Wh  + ((size_t)gate * HID + unit) * HID + kc * 8;
    const float* xrow = Wxp + ((size_t)gate * HID + unit) * HID + kc * 8;
    #pragma unroll
    for (int m = 0; m < 16; ++m) {
      const float4 q0 = *(const float4*)(wrow + m * 64);
      const float4 q1 = *(const float4*)(wrow + m * 64 + 4);
      w[m*8+0] = q0.x; w[m*8+1] = q0.y; w[m*8+2] = q0.z; w[m*8+3] = q0.w;
      w[m*8+4] = q1.x; w[m*8+5] = q1.y; w[m*8+6] = q1.z; w[m*8+7] = q1.w;
      const float4 p0 = *(const float4*)(xrow + m * 64);
      const float4 p1 = *(const float4*)(xrow + m * 64 + 4);
      uint4 pq;
      pq.x = pk(p0.x, p0.y); pq.y = pk(p0.z, p0.w);
      pq.z = pk(p1.x, p1.y); pq.w = pk(p1.z, p1.w);
      wx_lds[m * 256 + tid] = pq;
    }
  }

  // per-thread bias for this row (used by all kc lanes identically)
  const int brow = gate * HID + unit;
  const float bias = (d ? bxb[brow] : bxf[brow]) + (d ? bhb[brow] : bhf[brow]);

  unsigned long long* hx0 = h_ex + (size_t)(d * 2 + 0) * HID;
  unsigned long long* hx1 = h_ex + (size_t)(d * 2 + 1) * HID;
  unsigned int* fl0 = flg + (d * 2 + 0) * 128;
  unsigned int* fl1 = flg + (d * 2 + 1) * 128;

  const bool pub = ((lane & 31) == 0);         // kc==0 && gate==0: 8 lanes
  const int  ug  = db * 8 + wv * 2 + (lane >> 5);   // this pub lane's unit

  // self-zero exchange words (same lanes that later publish them ->
  // per-location program order guarantees zero precedes first real tag)
  if (pub) {
    __hip_atomic_store(hx0 + ug, 0ull, __ATOMIC_RELAXED, __HIP_MEMORY_SCOPE_AGENT);
    __hip_atomic_store(hx1 + ug, 0ull, __ATOMIC_RELAXED, __HIP_MEMORY_SCOPE_AGENT);
  }
  if (tid == 224) {                            // wave3 lane32: flag publisher
    __hip_atomic_store(fl0 + db, 0u, __ATOMIC_RELAXED, __HIP_MEMORY_SCOPE_AGENT);
    __hip_atomic_store(fl1 + db, 0u, __ATOMIC_RELAXED, __HIP_MEMORY_SCOPE_AGENT);
  }

  // tokens -> LDS; x(0) -> xbuf[0]
  tok_s[tid] = tokens[tid];
  tok_s[tid + 256] = tokens[tid + 256];
  {
    const int s0 = d ? (SEQ - 1) : 0;
    *(float4*)(&xbuf[0][tid * 4]) =
        *(const float4*)(emb + (size_t)tokens[s0] * HID + tid * 4);
  }
  __syncthreads();                             // covers wx_lds/xbuf/tok_s

  float c_state = 0.f;                         // on pub lanes only

  for (int t = 0; t < SEQ; ++t) {
    const int par  = t & 1;
    const int s_io = d ? (SEQ - 1 - t) : t;
    const bool pf  = (t + 1 < SEQ);

    // (1) x(t+1) prefetch into regs (full step of slack to cover it)
    float4 xf = {0.f, 0.f, 0.f, 0.f};
    if (pf) {
      const int sn = d ? (SEQ - 2 - t) : (t + 1);
      xf = *(const float4*)(emb + (size_t)tok_s[sn] * HID + tid * 4);
    }

    // (2) sentinel poll: 128 threads x 1 flag (4 lines/dir/par total)
    if (t > 0 && tid < 128) {
      const unsigned int* fp = (par ? fl0 : fl1) + tid;   // parity (t-1)&1
      while (__hip_atomic_load(fp, __ATOMIC_RELAXED, __HIP_MEMORY_SCOPE_AGENT)
             != (unsigned int)t)
        __builtin_amdgcn_s_sleep(1);
    }
    __syncthreads();                           // B1: all producers announced

    // (3) issue data loads, then overlap with xbuf write + acc_x
    const int base = tid * 4;
    const unsigned long long* hp = par ? hx0 : hx1;       // parity (t-1)&1
    unsigned long long u0 = 0, u1 = 0, u2 = 0, u3 = 0;
    if (t > 0) {
      u0 = __hip_atomic_load(hp+base+0, __ATOMIC_RELAXED, __HIP_MEMORY_SCOPE_AGENT);
      u1 = __hip_atomic_load(hp+base+1, __ATOMIC_RELAXED, __HIP_MEMORY_SCOPE_AGENT);
      u2 = __hip_atomic_load(hp+base+2, __ATOMIC_RELAXED, __HIP_MEMORY_SCOPE_AGENT);
      u3 = __hip_atomic_load(hp+base+3, __ATOMIC_RELAXED, __HIP_MEMORY_SCOPE_AGENT);
    }
    if (pf) *(float4*)(&xbuf[par ^ 1][tid * 4]) = xf;

    float axv[4] = {0.f, 0.f, 0.f, 0.f};
    {
      const float* xb = xbuf[par];
      #pragma unroll
      for (int m = 0; m < 16; ++m) {
        const uint4  wq = wx_lds[m * 256 + tid];
        const float4 a  = *(const float4*)(&xb[kc * 8 + m * 64]);
        const float4 c4 = *(const float4*)(&xb[kc * 8 + m * 64 + 4]);
        axv[m & 3] += bflo(wq.x) * a.x  + bfhi(wq.x) * a.y
                    + bflo(wq.y) * a.z  + bfhi(wq.y) * a.w
                    + bflo(wq.z) * c4.x + bfhi(wq.z) * c4.y
                    + bflo(wq.w) * c4.z + bfhi(wq.w) * c4.w;
      }
    }

    // (4) verify tags (stragglers rare: flags ~= data arrival), fill hs
    if (t == 0) {
      hs[base+0] = 0.f; hs[base+1] = 0.f; hs[base+2] = 0.f; hs[base+3] = 0.f;
    } else {
      const unsigned int need = (unsigned int)t;
      for (;;) {
        const bool o0 = (unsigned int)(u0 >> 32) == need;
        const bool o1 = (unsigned int)(u1 >> 32) == need;
        const bool o2 = (unsigned int)(u2 >> 32) == need;
        const bool o3 = (unsigned int)(u3 >> 32) == need;
        if (o0 & o1 & o2 & o3) break;
        if (!o0) u0 = __hip_atomic_load(hp+base+0, __ATOMIC_RELAXED, __HIP_MEMORY_SCOPE_AGENT);
        if (!o1) u1 = __hip_atomic_load(hp+base+1, __ATOMIC_RELAXED, __HIP_MEMORY_SCOPE_AGENT);
        if (!o2) u2 = __hip_atomic_load(hp+base+2, __ATOMIC_RELAXED, __HIP_MEMORY_SCOPE_AGENT);
        if (!o3) u3 = __hip_atomic_load(hp+base+3, __ATOMIC_RELAXED, __HIP_MEMORY_SCOPE_AGENT);
        __builtin_amdgcn_s_sleep(1);
      }
      hs[base+0] = __uint_as_float((unsigned int)u0);
      hs[base+1] = __uint_as_float((unsigned int)u1);
      hs[base+2] = __uint_as_float((unsigned int)u2);
      hs[base+3] = __uint_as_float((unsigned int)u3);
    }
    __syncthreads();                           // B2: hs ready

    // (5) stage b: Wh.h partial (4 accumulators)
    float ah[4] = {0.f, 0.f, 0.f, 0.f};
    #pragma unroll
    for (int m = 0; m < 16; ++m) {
      const float4 a  = *(const float4*)(&hs[kc * 8 + m * 64]);
      const float4 c4 = *(const float4*)(&hs[kc * 8 + m * 64 + 4]);
      ah[m & 3] += w[m*8+0] * a.x  + w[m*8+1] * a.y
                 + w[m*8+2] * a.z  + w[m*8+3] * a.w
                 + w[m*8+4] * c4.x + w[m*8+5] * c4.y
                 + w[m*8+6] * c4.z + w[m*8+7] * c4.w;
    }
    float acc = ((ah[0] + ah[1]) + (ah[2] + ah[3]))
              + ((axv[0] + axv[1]) + (axv[2] + axv[3]));
    acc += __shfl_xor(acc, 1);
    acc += __shfl_xor(acc, 2);
    acc += __shfl_xor(acc, 4);                 // all 8 kc lanes: row sum

    // (6) per-wave stage c: wave wv owns units 2wv, 2wv+1
    const float gsum = acc + bias;
    const float a = (gate == 3) ? ftanh(gsum) : sigm(gsum);
    const int gb = lane & 32;                  // unit sub-group base lane
    const float ai  = __shfl(a, gb + 0);
    const float af_ = __shfl(a, gb + 8);
    const float ao  = __shfl(a, gb + 16);
    const float ag  = __shfl(a, gb + 24);
    if (pub) {
      c_state = af_ * c_state + ai * ag;
      const float hv = ao * ftanh(c_state);
      const unsigned long long pkd =
          ((unsigned long long)(unsigned int)(t + 1) << 32)
        | (unsigned long long)__float_as_uint(hv);
      __hip_atomic_store((par ? hx1 : hx0) + ug, pkd,
                         __ATOMIC_RELAXED, __HIP_MEMORY_SCOPE_AGENT);
      out[(size_t)s_io * 2048 + d * HID + ug] = hv;
    }
    if (tid == 224)                            // after its own data store
      __hip_atomic_store((par ? fl1 : fl0) + db, (unsigned int)(t + 1),
                         __ATOMIC_RELAXED, __HIP_MEMORY_SCOPE_AGENT);
    // no end barrier: all step-(t+1) LDS writes occur after B1(t+1), which
    // follows every wave's stage_b/c of step t (program order + barrier).
  }
}

// ---------------------------------------------------------------------------
extern "C" void kernel_launch(void* const* d_in, const int* in_sizes, int n_in,
                              void* d_out, int out_size, void* d_ws, size_t ws_size,
                              hipStream_t stream) {
  const int*   tokens = (const int*)d_in[0];
  const float* emb = (const float*)d_in[3];
  const float* Wxf = (const float*)d_in[4];
  const float* Whf = (const float*)d_in[5];
  const float* bxf = (const float*)d_in[6];
  const float* bhf = (const float*)d_in[7];
  const float* Wxb = (const float*)d_in[8];
  const float* Whb = (const float*)d_in[9];
  const float* bxb = (const float*)d_in[10];
  const float* bhb = (const float*)d_in[11];

  char* ws = (char*)d_ws;
  unsigned long long* h_ex = (unsigned long long*)ws;          // 32 KB
  unsigned int* flg = (unsigned int*)(ws + 32 * 1024);          // 2 KB

  hipFuncSetAttribute((const void*)bilstm_kernel,
                      hipFuncAttributeMaxDynamicSharedMemorySize, 65536);

  bilstm_kernel<<<dim3(256), dim3(256), 65536, stream>>>(
      tokens, emb, Wxf, Whf, bxf, bhf, Wxb, Whb, bxb, bhb,
      h_ex, flg, (float*)d_out);
}

// Round 4
// 1661.378 us; speedup vs baseline: 1.8844x; 1.8844x over previous
//
#include <hip/hip_runtime.h>

// Bidirectional LSTM: V=32000, H=1024, S=512. fp32 in/out.
// SINGLE fused persistent kernel, 256 blocks x 256 threads (1 block/CU,
// grid == CU count -> all blocks co-resident).
//
// Round-4: direct data polling restored (round-3's flag indirection added a
// serial coherence hop + an inter-wave ordering hazard -> straggler spins).
//  - Exchange words stay self-announcing: u64 {tag=t+1 | fp32 h}, relaxed
//    agent-scope atomics, parity double-buffered.
//  - Each thread polls ONE word of its OWN producer group (the group's 8
//    words are stored by one wave ~simultaneously), then immediately issues
//    its 4 data loads; embedded tags re-verified after load (stragglers
//    rare, handled by reload loop). No block-wide barrier before the fetch.
//  - hs parity-double-buffered -> ONE __syncthreads per step (B1 before
//    stage_b). Ordering: fill(t+1) writes hs[par^1] after B1(t); stage_b(t-1)
//    reads hs[par^1] before B1(t) (program order through fill(t)+B1(t)) ->
//    separated. xbuf[par^1] write in step t: readers were acc_x(t-1) (before
//    B1(t-1)) and acc_x(t+1) (after B1(t)) -> separated by B1(t-1)/B1(t).
//  - Per-wave stage_c: wave owns 2 units; row sums wave-resident after the
//    kc-butterfly -> gates + combine via __shfl, no g_red, no 2nd barrier.
//  - acc_x split: m=0..7 before the poll (producer-visibility slack),
//    m=8..15 between data-load issue and verify (hides fetch latency).
//  - Self-zero of exchange words at init by their own future publishers
//    (kills stale-tag matches vs previous-dispatch residue).

#define HID 1024
#define SEQ 512

__device__ __forceinline__ unsigned int f2bf(float f) {
  union { float f; unsigned int i; } v; v.f = f;
  unsigned int u = v.i;
  return (u + 0x7fffu + ((u >> 16) & 1u)) >> 16;  // RNE
}
__device__ __forceinline__ unsigned int pk(float lo, float hi) {
  return f2bf(lo) | (f2bf(hi) << 16);
}
__device__ __forceinline__ float bflo(unsigned int u) {
  union { unsigned int i; float f; } v; v.i = u << 16; return v.f;
}
__device__ __forceinline__ float bfhi(unsigned int u) {
  union { unsigned int i; float f; } v; v.i = u & 0xffff0000u; return v.f;
}
__device__ __forceinline__ float sigm(float x) { return 1.f / (1.f + __expf(-x)); }
__device__ __forceinline__ float ftanh(float x) {
  return 1.f - 2.f / (__expf(2.f * x) + 1.f);   // exact at saturation
}

__global__ __launch_bounds__(256, 1)
void bilstm_kernel(const int* __restrict__ tokens,
                   const float* __restrict__ emb,
                   const float* __restrict__ Wxf, const float* __restrict__ Whf,
                   const float* __restrict__ bxf, const float* __restrict__ bhf,
                   const float* __restrict__ Wxb, const float* __restrict__ Whb,
                   const float* __restrict__ bxb, const float* __restrict__ bhb,
                   unsigned long long* h_ex,   // [2][2][1024] u64 {tag|h}
                   float* __restrict__ out)    // [SEQ][2048] fp32
{
  extern __shared__ unsigned char smem[];      // 64KB: wx bf16-packed
  uint4* wx_lds = (uint4*)smem;                // wx_lds[m*256 + tid]
  __shared__ alignas(16) float hs[2][HID];     // parity double buffer
  __shared__ alignas(16) float xbuf[2][HID];
  __shared__ int tok_s[SEQ];

  const int b   = blockIdx.x;
  const int d   = (b & 7) >> 2;                // dir by XCD half
  const int db  = (b >> 3) * 4 + (b & 3);      // 0..127 within direction
  const int tid = threadIdx.x;
  const int r   = tid >> 3;                    // 0..31: row = unit_l*4+gate
  const int kc  = tid & 7;                     // 8-way k split
  const int wv  = tid >> 6, lane = tid & 63;
  const int gate = r & 3;
  const int unit = db * 8 + (r >> 2);
  const float* Wh  = d ? Whb : Whf;
  const float* Wxp = d ? Wxb : Wxf;

  // --- init: Wh slice -> registers, Wx slice -> LDS (bf16 pairs) ---
  float w[128];
  {
    const float* wrow = Wh  + ((size_t)gate * HID + unit) * HID + kc * 8;
    const float* xrow = Wxp + ((size_t)gate * HID + unit) * HID + kc * 8;
    #pragma unroll
    for (int m = 0; m < 16; ++m) {
      const float4 q0 = *(const float4*)(wrow + m * 64);
      const float4 q1 = *(const float4*)(wrow + m * 64 + 4);
      w[m*8+0] = q0.x; w[m*8+1] = q0.y; w[m*8+2] = q0.z; w[m*8+3] = q0.w;
      w[m*8+4] = q1.x; w[m*8+5] = q1.y; w[m*8+6] = q1.z; w[m*8+7] = q1.w;
      const float4 p0 = *(const float4*)(xrow + m * 64);
      const float4 p1 = *(const float4*)(xrow + m * 64 + 4);
      uint4 pq;
      pq.x = pk(p0.x, p0.y); pq.y = pk(p0.z, p0.w);
      pq.z = pk(p1.x, p1.y); pq.w = pk(p1.z, p1.w);
      wx_lds[m * 256 + tid] = pq;
    }
  }

  const int brow = gate * HID + unit;
  const float bias = (d ? bxb[brow] : bxf[brow]) + (d ? bhb[brow] : bhf[brow]);

  unsigned long long* hx0 = h_ex + (size_t)(d * 2 + 0) * HID;
  unsigned long long* hx1 = h_ex + (size_t)(d * 2 + 1) * HID;

  const bool pub = ((lane & 31) == 0);         // lanes 0,32 of each wave
  const int  ug  = db * 8 + wv * 2 + (lane >> 5);

  // self-zero exchange words (same lanes that later publish them)
  if (pub) {
    __hip_atomic_store(hx0 + ug, 0ull, __ATOMIC_RELAXED, __HIP_MEMORY_SCOPE_AGENT);
    __hip_atomic_store(hx1 + ug, 0ull, __ATOMIC_RELAXED, __HIP_MEMORY_SCOPE_AGENT);
  }

  // tokens -> LDS; x(0) -> xbuf[0]
  tok_s[tid] = tokens[tid];
  tok_s[tid + 256] = tokens[tid + 256];
  {
    const int s0 = d ? (SEQ - 1) : 0;
    *(float4*)(&xbuf[0][tid * 4]) =
        *(const float4*)(emb + (size_t)tokens[s0] * HID + tid * 4);
  }
  __syncthreads();                             // covers wx_lds/xbuf/tok_s

  float c_state = 0.f;                         // on pub lanes only

  for (int t = 0; t < SEQ; ++t) {
    const int par  = t & 1;
    const int s_io = d ? (SEQ - 1 - t) : t;
    const bool pf  = (t + 1 < SEQ);

    // (1) x(t+1) gather into regs (covered by poll + acc_x)
    float4 xf = {0.f, 0.f, 0.f, 0.f};
    if (pf) {
      const int sn = d ? (SEQ - 2 - t) : (t + 1);
      xf = *(const float4*)(emb + (size_t)tok_s[sn] * HID + tid * 4);
    }

    // (2) acc_x part 1 (m=0..7) on xbuf[par] — producer-visibility slack
    float axv[4] = {0.f, 0.f, 0.f, 0.f};
    const float* xb = xbuf[par];
    #pragma unroll
    for (int m = 0; m < 8; ++m) {
      const uint4  wq = wx_lds[m * 256 + tid];
      const float4 a  = *(const float4*)(&xb[kc * 8 + m * 64]);
      const float4 c4 = *(const float4*)(&xb[kc * 8 + m * 64 + 4]);
      axv[m & 3] += bflo(wq.x) * a.x  + bfhi(wq.x) * a.y
                  + bflo(wq.y) * a.z  + bfhi(wq.y) * a.w
                  + bflo(wq.z) * c4.x + bfhi(wq.z) * c4.y
                  + bflo(wq.w) * c4.z + bfhi(wq.w) * c4.w;
    }

    // (3) poll OWN producer group's sentinel word (group = 64B, stored by
    //     one wave ~simultaneously), then issue own 4 data loads.
    const int base = tid * 4;
    const unsigned long long* hp = par ? hx0 : hx1;   // read buf = par^1
    unsigned long long u0 = 0, u1 = 0, u2 = 0, u3 = 0;
    if (t > 0) {
      const unsigned int need = (unsigned int)t;
      const unsigned long long* sp = hp + (tid >> 1) * 8;
      unsigned long long s =
          __hip_atomic_load(sp, __ATOMIC_RELAXED, __HIP_MEMORY_SCOPE_AGENT);
      while ((unsigned int)(s >> 32) != need) {
        __builtin_amdgcn_s_sleep(1);
        s = __hip_atomic_load(sp, __ATOMIC_RELAXED, __HIP_MEMORY_SCOPE_AGENT);
      }
      u0 = __hip_atomic_load(hp+base+0, __ATOMIC_RELAXED, __HIP_MEMORY_SCOPE_AGENT);
      u1 = __hip_atomic_load(hp+base+1, __ATOMIC_RELAXED, __HIP_MEMORY_SCOPE_AGENT);
      u2 = __hip_atomic_load(hp+base+2, __ATOMIC_RELAXED, __HIP_MEMORY_SCOPE_AGENT);
      u3 = __hip_atomic_load(hp+base+3, __ATOMIC_RELAXED, __HIP_MEMORY_SCOPE_AGENT);
    }

    // (4) acc_x part 2 (m=8..15) — hides the data-fetch latency
    #pragma unroll
    for (int m = 8; m < 16; ++m) {
      const uint4  wq = wx_lds[m * 256 + tid];
      const float4 a  = *(const float4*)(&xb[kc * 8 + m * 64]);
      const float4 c4 = *(const float4*)(&xb[kc * 8 + m * 64 + 4]);
      axv[m & 3] += bflo(wq.x) * a.x  + bfhi(wq.x) * a.y
                  + bflo(wq.y) * a.z  + bfhi(wq.y) * a.w
                  + bflo(wq.z) * c4.x + bfhi(wq.z) * c4.y
                  + bflo(wq.w) * c4.z + bfhi(wq.w) * c4.w;
    }

    // (5) x(t+1) -> xbuf[par^1] (safe: see ordering note in header)
    if (pf) *(float4*)(&xbuf[par ^ 1][tid * 4]) = xf;

    // (6) verify tags, fill hs[par]
    float* hcur = hs[par];
    if (t == 0) {
      hcur[base+0] = 0.f; hcur[base+1] = 0.f;
      hcur[base+2] = 0.f; hcur[base+3] = 0.f;
    } else {
      const unsigned int need = (unsigned int)t;
      for (;;) {
        const bool o0 = (unsigned int)(u0 >> 32) == need;
        const bool o1 = (unsigned int)(u1 >> 32) == need;
        const bool o2 = (unsigned int)(u2 >> 32) == need;
        const bool o3 = (unsigned int)(u3 >> 32) == need;
        if (o0 & o1 & o2 & o3) break;
        if (!o0) u0 = __hip_atomic_load(hp+base+0, __ATOMIC_RELAXED, __HIP_MEMORY_SCOPE_AGENT);
        if (!o1) u1 = __hip_atomic_load(hp+base+1, __ATOMIC_RELAXED, __HIP_MEMORY_SCOPE_AGENT);
        if (!o2) u2 = __hip_atomic_load(hp+base+2, __ATOMIC_RELAXED, __HIP_MEMORY_SCOPE_AGENT);
        if (!o3) u3 = __hip_atomic_load(hp+base+3, __ATOMIC_RELAXED, __HIP_MEMORY_SCOPE_AGENT);
      }
      hcur[base+0] = __uint_as_float((unsigned int)u0);
      hcur[base+1] = __uint_as_float((unsigned int)u1);
      hcur[base+2] = __uint_as_float((unsigned int)u2);
      hcur[base+3] = __uint_as_float((unsigned int)u3);
    }
    __syncthreads();                           // B1: hs[par] complete

    // (7) stage b: Wh.h partial (4 accumulators)
    float ah[4] = {0.f, 0.f, 0.f, 0.f};
    #pragma unroll
    for (int m = 0; m < 16; ++m) {
      const float4 a  = *(const float4*)(&hcur[kc * 8 + m * 64]);
      const float4 c4 = *(const float4*)(&hcur[kc * 8 + m * 64 + 4]);
      ah[m & 3] += w[m*8+0] * a.x  + w[m*8+1] * a.y
                 + w[m*8+2] * a.z  + w[m*8+3] * a.w
                 + w[m*8+4] * c4.x + w[m*8+5] * c4.y
                 + w[m*8+6] * c4.z + w[m*8+7] * c4.w;
    }
    float acc = ((ah[0] + ah[1]) + (ah[2] + ah[3]))
              + ((axv[0] + axv[1]) + (axv[2] + axv[3]));
    acc += __shfl_xor(acc, 1);
    acc += __shfl_xor(acc, 2);
    acc += __shfl_xor(acc, 4);                 // all 8 kc lanes: row sum

    // (8) per-wave stage c: wave wv owns units 2wv, 2wv+1
    const float gsum = acc + bias;
    const float a = (gate == 3) ? ftanh(gsum) : sigm(gsum);
    const int gb = lane & 32;
    const float ai  = __shfl(a, gb + 0);
    const float af_ = __shfl(a, gb + 8);
    const float ao  = __shfl(a, gb + 16);
    const float ag  = __shfl(a, gb + 24);
    if (pub) {
      c_state = af_ * c_state + ai * ag;
      const float hv = ao * ftanh(c_state);
      const unsigned long long pkd =
          ((unsigned long long)(unsigned int)(t + 1) << 32)
        | (unsigned long long)__float_as_uint(hv);
      __hip_atomic_store((par ? hx1 : hx0) + ug, pkd,
                         __ATOMIC_RELAXED, __HIP_MEMORY_SCOPE_AGENT);
      out[(size_t)s_io * 2048 + d * HID + ug] = hv;
    }
    // single barrier per step: hs/xbuf hazards ordered via parity buffers
  }
}

// ---------------------------------------------------------------------------
extern "C" void kernel_launch(void* const* d_in, const int* in_sizes, int n_in,
                              void* d_out, int out_size, void* d_ws, size_t ws_size,
                              hipStream_t stream) {
  const int*   tokens = (const int*)d_in[0];
  const float* emb = (const float*)d_in[3];
  const float* Wxf = (const float*)d_in[4];
  const float* Whf = (const float*)d_in[5];
  const float* bxf = (const float*)d_in[6];
  const float* bhf = (const float*)d_in[7];
  const float* Wxb = (const float*)d_in[8];
  const float* Whb = (const float*)d_in[9];
  const float* bxb = (const float*)d_in[10];
  const float* bhb = (const float*)d_in[11];

  unsigned long long* h_ex = (unsigned long long*)d_ws;   // 32 KB

  hipFuncSetAttribute((const void*)bilstm_kernel,
                      hipFuncAttributeMaxDynamicSharedMemorySize, 65536);

  bilstm_kernel<<<dim3(256), dim3(256), 65536, stream>>>(
      tokens, emb, Wxf, Whf, bxf, bhf, Wxb, Whb, bxb, bhb,
      h_ex, (float*)d_out);
}